// Round 1
// baseline (134.342 us; speedup 1.0000x reference)
//
#include <hip/hip_runtime.h>

// Problem constants (from reference): B=20000, C=64, D=27
// out0: (B,C,9,9)  = T1(B,C,9,3) @ T2(B,3,9)  * 1/sqrt(3)
// out1: (B,C,3,3)  = T1(B,C,3,9) @ T2(B,9,3)  * 1/3
// out2: (B,C)      = dot(T1(B,C,27), T2(B,27)) * 1/sqrt(27)

constexpr int C_DIM     = 64;
constexpr int D_DIM     = 27;
constexpr int T1_PER_B  = C_DIM * D_DIM;   // 1728
constexpr int OUT0_PER_B = C_DIM * 81;     // 5184
constexpr int OUT1_PER_B = C_DIM * 9;      // 576
constexpr int OUT2_PER_B = C_DIM;          // 64

__global__ __launch_bounds__(256) void atc_kernel(
    const float* __restrict__ T1, const float* __restrict__ T2,
    float* __restrict__ out0, float* __restrict__ out1, float* __restrict__ out2,
    int B)
{
    __shared__ float s1[T1_PER_B];   // T1[b] tile, 6912 B
    __shared__ float s2[32];         // T2[b], 27 used

    const int tid = threadIdx.x;
    const float n0 = 0.57735026918962576f;  // 1/sqrt(3)
    const float n1 = 0.33333333333333333f;  // 1/3
    const float n2 = 0.19245008972987526f;  // 1/sqrt(27)

    for (int b = blockIdx.x; b < B; b += gridDim.x) {
        // ---- stage T1[b] (1728 f32) + T2[b] (27 f32) into LDS, coalesced f4 ----
        const float4* t1v = reinterpret_cast<const float4*>(T1 + (size_t)b * T1_PER_B);
        float4* s1v = reinterpret_cast<float4*>(s1);
        #pragma unroll
        for (int i = tid; i < T1_PER_B / 4; i += 256) s1v[i] = t1v[i];
        if (tid < D_DIM) s2[tid] = T2[(size_t)b * D_DIM + tid];
        __syncthreads();

        // ---- out0: 5184 f32 = 1296 float4, coalesced ----
        float4* o0 = reinterpret_cast<float4*>(out0 + (size_t)b * OUT0_PER_B);
        for (int f = tid; f < OUT0_PER_B / 4; f += 256) {
            float4 r;
            #pragma unroll
            for (int u = 0; u < 4; ++u) {
                const int e  = f * 4 + u;
                const int c  = e / 81;
                const int ij = e - c * 81;
                const int i  = ij / 9;
                const int j  = ij - i * 9;
                const float* a = s1 + c * 27 + i * 3;
                float v = a[0] * s2[j] + a[1] * s2[9 + j] + a[2] * s2[18 + j];
                (&r.x)[u] = v * n0;
            }
            o0[f] = r;
        }

        // ---- out1: 576 f32 = 144 float4, coalesced ----
        float4* o1 = reinterpret_cast<float4*>(out1 + (size_t)b * OUT1_PER_B);
        for (int f = tid; f < OUT1_PER_B / 4; f += 256) {
            float4 r;
            #pragma unroll
            for (int u = 0; u < 4; ++u) {
                const int e  = f * 4 + u;
                const int c  = e / 9;
                const int ij = e - c * 9;
                const int i  = ij / 3;
                const int j  = ij - i * 3;
                const float* a = s1 + c * 27 + i * 9;
                float v = 0.f;
                #pragma unroll
                for (int k = 0; k < 9; ++k) v += a[k] * s2[k * 3 + j];
                (&r.x)[u] = v * n1;
            }
            o1[f] = r;
        }

        // ---- out2: 64 f32, coalesced scalar ----
        if (tid < C_DIM) {
            const float* a = s1 + tid * 27;
            float v = 0.f;
            #pragma unroll
            for (int d = 0; d < D_DIM; ++d) v += a[d] * s2[d];
            out2[(size_t)b * OUT2_PER_B + tid] = v * n2;
        }
        __syncthreads();  // protect LDS before next b's staging
    }
}

extern "C" void kernel_launch(void* const* d_in, const int* in_sizes, int n_in,
                              void* d_out, int out_size, void* d_ws, size_t ws_size,
                              hipStream_t stream) {
    const float* T1 = (const float*)d_in[0];
    const float* T2 = (const float*)d_in[1];
    float* out = (float*)d_out;

    const int B = in_sizes[0] / T1_PER_B;   // 20000

    float* out0 = out;
    float* out1 = out0 + (size_t)B * OUT0_PER_B;
    float* out2 = out1 + (size_t)B * OUT1_PER_B;

    const int blocks = (B < 2048) ? B : 2048;
    atc_kernel<<<dim3(blocks), dim3(256), 0, stream>>>(T1, T2, out0, out1, out2, B);
}

// Round 2
// 125.287 us; speedup vs baseline: 1.0723x; 1.0723x over previous
//
#include <hip/hip_runtime.h>

// B=20000, C=64, D=27
// out0[b,c,i,j] = sum_k T1[b,c,3i+k] * T2[b,9k+j] / sqrt(3)   (i,j in 0..8, k in 0..2)
// out1[b,c,i,j] = sum_k T1[b,c,9i+k] * T2[b,3k+j] / 3         (i,j in 0..2, k in 0..8)
// out2[b,c]     = sum_d T1[b,c,d]    * T2[b,d]    / sqrt(27)

constexpr int C_DIM      = 64;
constexpr int D_DIM      = 27;
constexpr int T1_PER_B   = C_DIM * D_DIM;   // 1728
constexpr int OUT0_PER_B = C_DIM * 81;      // 5184
constexpr int OUT1_PER_B = C_DIM * 9;       // 576
constexpr int OUT2_PER_B = C_DIM;           // 64

__global__ __launch_bounds__(256) void atc_kernel(
    const float* __restrict__ T1, const float* __restrict__ T2,
    float* __restrict__ out0, float* __restrict__ out1, float* __restrict__ out2,
    int B)
{
    // LDS: T1 tile + output transpose buffers (all 16B-aligned for b128 access)
    __shared__ __align__(16) float sT1[T1_PER_B];    //  6912 B
    __shared__ __align__(16) float sO0[OUT0_PER_B];  // 20736 B
    __shared__ __align__(16) float sO1[OUT1_PER_B];  //  2304 B
    // total 29,952 B -> 5 blocks/CU -> 20 waves/CU

    const int tid = threadIdx.x;

    // out0 row assignment: 576 rows (r = 9c+i) over 256 threads: 2 or 3 rows each.
    // r_start = floor(9*tid/4); a-base = 3r (since 27c+3i = 3(9c+i)); out-base = 9r.
    const int r_start = (9 * tid) >> 2;
    const int nrows   = ((9 * (tid + 1)) >> 2) - r_start;

    const float n0 = 0.57735026918962576f;  // 1/sqrt(3)
    const float n1 = 0.33333333333333333f;  // 1/3
    const float n2 = 0.19245008972987526f;  // 1/sqrt(27)

    for (int b = blockIdx.x; b < B; b += gridDim.x) {
        // ---- T2[b] into registers, compile-time indexed (uniform loads) ----
        const float* t2p = T2 + (size_t)b * D_DIM;
        float s2[D_DIM];
        #pragma unroll
        for (int d = 0; d < D_DIM; ++d) s2[d] = t2p[d];

        // ---- stage T1[b] (432 float4), coalesced ----
        const float4* t1v = reinterpret_cast<const float4*>(T1 + (size_t)b * T1_PER_B);
        float4* sv = reinterpret_cast<float4*>(sT1);
        sv[tid] = t1v[tid];
        if (tid < 176) sv[256 + tid] = t1v[256 + tid];
        __syncthreads();

        // ---- out0: 2-3 rows per thread; 3 LDS reads per 9 outputs ----
        for (int s = 0; s < nrows; ++s) {
            const int r = r_start + s;
            const float a0 = sT1[3 * r];
            const float a1 = sT1[3 * r + 1];
            const float a2 = sT1[3 * r + 2];
            #pragma unroll
            for (int j = 0; j < 9; ++j) {
                sO0[9 * r + j] = (a0 * s2[j] + a1 * s2[9 + j] + a2 * s2[18 + j]) * n0;
            }
        }

        // ---- out1: threads 0..191, one (c,i) row each; a-base = 9*tid ----
        if (tid < 192) {
            const float* a = sT1 + 9 * tid;
            #pragma unroll
            for (int j = 0; j < 3; ++j) {
                float v = 0.f;
                #pragma unroll
                for (int k = 0; k < 9; ++k) v += a[k] * s2[3 * k + j];
                sO1[3 * tid + j] = v * n1;
            }
        }

        // ---- out2: threads 192..255 (wave 3), direct coalesced store ----
        if (tid >= 192) {
            const int c = tid - 192;
            const float* a = sT1 + D_DIM * c;
            float v = 0.f;
            #pragma unroll
            for (int d = 0; d < D_DIM; ++d) v += a[d] * s2[d];
            out2[(size_t)b * OUT2_PER_B + c] = v * n2;
        }
        __syncthreads();

        // ---- coalesced float4 readback + store ----
        float4* o0 = reinterpret_cast<float4*>(out0 + (size_t)b * OUT0_PER_B);
        const float4* s0v = reinterpret_cast<const float4*>(sO0);
        #pragma unroll
        for (int q = 0; q < 5; ++q) o0[q * 256 + tid] = s0v[q * 256 + tid];
        if (tid < 16) o0[1280 + tid] = s0v[1280 + tid];

        float4* o1 = reinterpret_cast<float4*>(out1 + (size_t)b * OUT1_PER_B);
        const float4* s1v = reinterpret_cast<const float4*>(sO1);
        if (tid < 144) o1[tid] = s1v[tid];
        // No end-of-loop barrier needed: a thread reaches its next-iter sT1/sO*
        // writes only after passing this iteration's second __syncthreads(),
        // which guarantees all threads finished their reads.
    }
}

extern "C" void kernel_launch(void* const* d_in, const int* in_sizes, int n_in,
                              void* d_out, int out_size, void* d_ws, size_t ws_size,
                              hipStream_t stream) {
    const float* T1 = (const float*)d_in[0];
    const float* T2 = (const float*)d_in[1];
    float* out = (float*)d_out;

    const int B = in_sizes[0] / T1_PER_B;   // 20000

    float* out0 = out;
    float* out1 = out0 + (size_t)B * OUT0_PER_B;
    float* out2 = out1 + (size_t)B * OUT1_PER_B;

    const int blocks = (B < 2048) ? B : 2048;
    atc_kernel<<<dim3(blocks), dim3(256), 0, stream>>>(T1, T2, out0, out1, out2, B);
}